// Round 8
// baseline (658.240 us; speedup 1.0000x reference)
//
#include <hip/hip_runtime.h>
#include <cstdint>
#include <cstddef>

#define BATCH 32768
#define NHID 256
#define KTOT 2048                    // NHID * 8
#define MAT_ELEMS (NHID * KTOT)      // 524288 elements per weight matrix
#define CHUNK_SHORTS (16 * 64 * 8)   // 8192 shorts = 16KB per K-chunk of packed W
#define PHASES 8
#define CPP 8                        // chunks per phase (64 / PHASES)
#define FPP 32                       // feats per phase (256 / PHASES)

typedef __attribute__((ext_vector_type(8))) short short8;
typedef __attribute__((ext_vector_type(4))) float f32x4;
typedef __attribute__((ext_vector_type(4))) int int4v;

__device__ __forceinline__ float fast_tanh(float x) {
    // t = 1 - 2/(e^{2x}+1); monotone, |t|<1, no NaN/Inf for any finite x
    float e = __expf(2.0f * x);
    return 1.0f - 2.0f / (e + 1.0f);
}

__device__ __forceinline__ unsigned short f2bf(float f) {
    union { float f; unsigned u; } v; v.f = f;
    unsigned r = v.u + 0x7fffu + ((v.u >> 16) & 1u);  // RNE (prepack only)
    return (unsigned short)(r >> 16);
}

// lgkm-only barrier (CK idiom): LDS handoff without draining vmcnt —
// in-flight global prefetches (weights, next-phase act) survive the barrier.
__device__ __forceinline__ void block_sync_lds() {
    asm volatile("s_waitcnt lgkmcnt(0)" ::: "memory");
    __builtin_amdgcn_s_barrier();
    asm volatile("" ::: "memory");
}

// T0..T7 of tanh(hv), packed to 8 bf16 in an int4: round-half-up + v_perm pack
__device__ __forceinline__ int4v cheb_pack(float hv) {
    float t = fast_tanh(hv);
    float t2 = t + t;
    unsigned u[8];
    union { float f; unsigned q; } c;
    u[0] = 0x3f800000u;              // T0 = 1.0
    c.f = t; u[1] = c.q;             // T1 = t
    float Tm = 1.0f, Tc = t;
#pragma unroll
    for (int d = 2; d < 8; ++d) {
        float Tn = fmaf(t2, Tc, -Tm);   // T_d = 2t*T_{d-1} - T_{d-2}
        c.f = Tn; u[d] = c.q;
        Tm = Tc; Tc = Tn;
    }
#pragma unroll
    for (int i = 0; i < 8; ++i) u[i] += 0x8000u;   // round-half-up to bf16
    int4v p;
    p.x = (int)__builtin_amdgcn_perm(u[1], u[0], 0x07060302);
    p.y = (int)__builtin_amdgcn_perm(u[3], u[2], 0x07060302);
    p.z = (int)__builtin_amdgcn_perm(u[5], u[4], 0x07060302);
    p.w = (int)__builtin_amdgcn_perm(u[7], u[6], 0x07060302);
    return p;
}

// ---------------------------------------------------------------- RFF embed (transposed out)
// hT[j][b] layout: feature-major, batch contiguous.
__global__ __launch_bounds__(256) void kan_rff(
    const float* __restrict__ x, const float* __restrict__ B, float* __restrict__ hT)
{
    int b = blockIdx.x * 256 + threadIdx.x;
    int j = blockIdx.y;   // 0..127
    float x0 = x[b * 3 + 0], x1 = x[b * 3 + 1], x2 = x[b * 3 + 2];
    float z = x0 * B[j] + x1 * B[128 + j] + x2 * B[256 + j];
    float sn, cs;
    __sincosf(z, &sn, &cs);
    hT[(size_t)j * BATCH + b] = cs;
    hT[(size_t)(j + 128) * BATCH + b] = sn;
}

// ------------------------------------------------- weight prepack to bf16 A-frag order
// pw[((kc*16 + nt)*64 + lane)*8 + j] = bf16( W[nt*16 + (lane&15)][kc*32 + (lane>>4)*8 + j] )
__global__ __launch_bounds__(256) void kan_prepack(
    const float* __restrict__ CU, const float* __restrict__ CV,
    const float* __restrict__ Cin, const float* __restrict__ Cout,
    unsigned short* __restrict__ pw)
{
    int mat = blockIdx.y;   // 0=CU 1=CV 2..5=Cin[i] 6..9=Cout[i]
    const float* src;
    if (mat == 0) src = CU;
    else if (mat == 1) src = CV;
    else if (mat < 6) src = Cin + (size_t)(mat - 2) * MAT_ELEMS;
    else src = Cout + (size_t)(mat - 6) * MAT_ELEMS;
    unsigned short* dst = pw + (size_t)mat * MAT_ELEMS;

    int p8 = blockIdx.x * 256 + threadIdx.x;   // 0..65535 (16B groups)
    int l  = p8 & 63;
    int nt = (p8 >> 6) & 15;
    int kc = p8 >> 10;
    int o = nt * 16 + (l & 15);
    int k = kc * 32 + ((l >> 4) << 3);
    const float* s = src + (size_t)o * KTOT + k;
    short8 v;
#pragma unroll
    for (int j = 0; j < 8; ++j) v[j] = (short)f2bf(s[j]);
    *(short8*)(dst + (size_t)p8 * 8) = v;
}

// ---------------------------------------------------------------- fused KAN GEMM
// Block = 64-batch tile x ALL 256 outs -> basis computed ONCE per (batch,k)
// device-wide. K phased in 8ths: phase = 32 feats x 64 batch basis in 32KB
// LDS, then a barrier-free 8-chunk MFMA run (weights global->VGPR prefetched;
// basis via contiguous conflict-free ds_read_b128). 16 lgkm-only barriers.
// 32KB LDS -> mode-1 (256 thr) fits 4 blocks/CU: co-resident blocks fill
// each other's barrier stalls.
// NT=512 (uv): waves 0-3 -> U (pw0/out0), 4-7 -> V (pw1/out1), shared basis.
// NT=256 (res): 4 waves, MODE=1 epilogue: out = s*(v+g*(u-v)) + (1-s)*idb.
template<int NT, int MODE>
__global__ __launch_bounds__(NT, (NT == 512) ? 2 : 4) void kan_gemm(
    const float* __restrict__ actT,
    const unsigned short* __restrict__ pw0,
    const unsigned short* __restrict__ pw1,
    float* out0, float* out1,
    const float* __restrict__ uT, const float* __restrict__ vT,
    const float* idbT, const float* __restrict__ scal)
{
    constexpr int ROWS = FPP * 64 / NT;   // feat rows per thread per phase: 4 or 8
    __shared__ __attribute__((aligned(16))) unsigned short bas[FPP * 64 * 8]; // 32KB

    const int tid = threadIdx.x;
    const int wv = tid >> 6, lane = tid & 63;
    const int os = (NT == 512) ? (wv & 3) : wv;   // out-split 0..3 (64 outs)
    const int sel = (NT == 512) ? (wv >> 2) : 0;
    const int b0 = blockIdx.x * 64;

    const unsigned short* pw = sel ? pw1 : pw0;
    float* outp = sel ? out1 : out0;

    f32x4 acc[4][4];   // [mf][nf]
#pragma unroll
    for (int i = 0; i < 4; ++i)
#pragma unroll
        for (int j = 0; j < 4; ++j)
            acc[i][j] = (f32x4){0.f, 0.f, 0.f, 0.f};

    // --- fill role: thread covers batch bb, feats fgrp*ROWS + q (within phase)
    const int bb = tid & 63;
    const int fgrp = tid >> 6;
    const float* actcol = actT + b0 + bb;
    unsigned short* bw = &bas[(size_t)(fgrp * ROWS * 64 + bb) * 8];

    // --- A (weights) per-lane stream base: ((kc*16 + os*4+mf)*64 + lane)*8
    const unsigned short* pA = pw + (size_t)(os * 4 * 64 + lane) * 8;

    float hv[ROWS], hvn[ROWS];
#pragma unroll
    for (int q = 0; q < ROWS; ++q)
        hv[q] = actcol[(size_t)(fgrp * ROWS + q) * BATCH];

    short8 a_cur[4];
#pragma unroll
    for (int mf = 0; mf < 4; ++mf)
        a_cur[mf] = *(const short8*)(pA + mf * 512);
    const unsigned short* pAn = pA + CHUNK_SHORTS;   // next chunk to prefetch

#pragma unroll 1
    for (int phase = 0; phase < PHASES; ++phase) {
        block_sync_lds();   // all consumers of previous phase done
#pragma unroll
        for (int q = 0; q < ROWS; ++q)
            *(int4v*)(bw + q * 512) = cheb_pack(hv[q]);
        // prefetch next phase's act values (wrap at end: harmless re-read)
        {
            const int pn = (phase + 1) & (PHASES - 1);
            const float* ac = actcol + (size_t)(pn * FPP + fgrp * ROWS) * BATCH;
#pragma unroll
            for (int q = 0; q < ROWS; ++q)
                hvn[q] = ac[(size_t)q * BATCH];
        }
        block_sync_lds();   // fill visible; weight prefetches still in flight
#pragma unroll
        for (int kcl = 0; kcl < CPP; ++kcl) {
            short8 a_nxt[4];
#pragma unroll
            for (int mf = 0; mf < 4; ++mf)
                a_nxt[mf] = *(const short8*)(pAn + (size_t)kcl * CHUNK_SHORTS + mf * 512);
            // (after last chunk this overruns into the next matrix / acts: harmless)
#pragma unroll
            for (int nf = 0; nf < 4; ++nf) {
                short8 bfr = *(const short8*)&bas[
                    ((kcl * 4 + (lane >> 4)) * 64 + nf * 16 + (lane & 15)) * 8];
#pragma unroll
                for (int mf = 0; mf < 4; ++mf)
                    acc[mf][nf] = __builtin_amdgcn_mfma_f32_16x16x32_bf16(
                        a_cur[mf], bfr, acc[mf][nf], 0, 0, 0);
            }
#pragma unroll
            for (int mf = 0; mf < 4; ++mf) a_cur[mf] = a_nxt[mf];
        }
        pAn += CPP * (size_t)CHUNK_SHORTS;
#pragma unroll
        for (int q = 0; q < ROWS; ++q) hv[q] = hvn[q];
    }

    // --- epilogue: D row (M) = out, col (N) = batch; row=(lane>>4)*4+reg, col=lane&15
    const int col = lane & 15;
    const int rb = (lane >> 4) * 4;
    float s = 0.f;
    if (MODE == 1) s = *scal;
#pragma unroll
    for (int mf = 0; mf < 4; ++mf) {
#pragma unroll
        for (int nf = 0; nf < 4; ++nf) {
            int b = b0 + nf * 16 + col;
#pragma unroll
            for (int r = 0; r < 4; ++r) {
                int orow = os * 64 + mf * 16 + rb + r;
                size_t idx = (size_t)orow * BATCH + b;
                float g = acc[mf][nf][r];
                if (MODE == 0) {
                    outp[idx] = g;
                } else {
                    // idb may alias outp: same-thread read-then-write — safe
                    float uu = uT[idx], vvv = vT[idx], id = idbT[idx];
                    outp[idx] = s * (vvv + g * (uu - vvv)) + (1.0f - s) * id;
                }
            }
        }
    }
}

// ---------------------------------------------------------------- final layer (N_OUT=1)
// One thread per batch element; hT reads coalesced; C_final broadcast from LDS.
__global__ __launch_bounds__(64) void kan_final(
    const float* __restrict__ hT, const float* __restrict__ Cf, float* __restrict__ out)
{
    __shared__ float cf[KTOT];
    const int tid = threadIdx.x;
    for (int i = tid; i < KTOT; i += 64) cf[i] = Cf[i];
    __syncthreads();
    int b = blockIdx.x * 64 + tid;
    float a = 0.f;
#pragma unroll 4
    for (int i = 0; i < NHID; ++i) {
        float t = fast_tanh(hT[(size_t)i * BATCH + b]);
        const float* c = &cf[i * 8];
        float accv = fmaf(c[1], t, c[0]);
        float t2 = t + t, Tm = 1.0f, Tc = t;
#pragma unroll
        for (int d = 2; d < 8; ++d) {
            float Tn = fmaf(t2, Tc, -Tm);
            accv = fmaf(c[d], Tn, accv);
            Tm = Tc; Tc = Tn;
        }
        a += accv;
    }
    out[b] = a;
}

// ---------------------------------------------------------------- launch
extern "C" void kernel_launch(void* const* d_in, const int* in_sizes, int n_in,
                              void* d_out, int out_size, void* d_ws, size_t ws_size,
                              hipStream_t stream)
{
    const float* x      = (const float*)d_in[0];
    const float* Brff   = (const float*)d_in[1];
    const float* CU     = (const float*)d_in[2];
    const float* CV     = (const float*)d_in[3];
    const float* Cin    = (const float*)d_in[4];
    const float* Cout   = (const float*)d_in[5];
    const float* alphas = (const float*)d_in[6];
    const float* betas  = (const float*)d_in[7];
    const float* Cf     = (const float*)d_in[8];
    float* out = (float*)d_out;

    char* ws = (char*)d_ws;
    const size_t PW_BYTES  = (size_t)10 * MAT_ELEMS * sizeof(unsigned short); // 10.5 MB
    const size_t ACT_BYTES = (size_t)BATCH * NHID * sizeof(float);            // 33.5 MB
    unsigned short* pw = (unsigned short*)ws;    // pw FIRST: tail overrun lands in acts
    float* P = (float*)(ws + PW_BYTES);                  // h ping
    float* Q = (float*)(ws + PW_BYTES + ACT_BYTES);      // h pong / t1
    float* u = (float*)(ws + PW_BYTES + 2 * ACT_BYTES);
    float* v = (float*)(ws + PW_BYTES + 3 * ACT_BYTES);

    kan_rff<<<dim3(BATCH / 256, 128), 256, 0, stream>>>(x, Brff, P);
    kan_prepack<<<dim3(256, 10), 256, 0, stream>>>(CU, CV, Cin, Cout, pw);

    // u and v in ONE dispatch: 8-wave blocks share the basis across U and V
    kan_gemm<512, 0><<<dim3(BATCH / 64), 512, 0, stream>>>(
        P, pw, pw + MAT_ELEMS, u, v, nullptr, nullptr, nullptr, nullptr);

    for (int i = 0; i < 4; ++i) {
        const unsigned short* pwIn  = pw + (size_t)(2 + i) * MAT_ELEMS;
        const unsigned short* pwOut = pw + (size_t)(6 + i) * MAT_ELEMS;
        // t1 = beta*(v + g(h)*(u-v)) + (1-beta)*h        : act=P, out=Q
        kan_gemm<256, 1><<<dim3(BATCH / 64), 256, 0, stream>>>(
            P, pwIn, nullptr, Q, nullptr, u, v, P, betas + i);
        // h' = alpha*(v + g(t1)*(u-v)) + (1-alpha)*h     : act=Q, idb=P, out=P
        kan_gemm<256, 1><<<dim3(BATCH / 64), 256, 0, stream>>>(
            Q, pwOut, nullptr, P, nullptr, u, v, P, alphas + i);
    }

    kan_final<<<BATCH / 64, 64, 0, stream>>>(P, Cf, out);
}

// Round 9
// 594.826 us; speedup vs baseline: 1.1066x; 1.1066x over previous
//
#include <hip/hip_runtime.h>
#include <cstdint>
#include <cstddef>

#define BATCH 32768
#define NHID 256
#define KTOT 2048                    // NHID * 8
#define MAT_ELEMS (NHID * KTOT)      // 524288 elements per weight matrix
#define CHUNK_SHORTS (16 * 64 * 8)   // 8192 shorts = 16KB per K-chunk of packed W
#define PHASES 8
#define CPP 8                        // chunks per phase (64 / PHASES); 8 % 4 == 0 (rotbuf!)
#define FPP 32                       // feats per phase (256 / PHASES)

typedef __attribute__((ext_vector_type(8))) short short8;
typedef __attribute__((ext_vector_type(4))) float f32x4;
typedef __attribute__((ext_vector_type(4))) int int4v;
typedef unsigned short ushort;

__device__ __forceinline__ float fast_tanh(float x) {
    // t = 1 - 2/(e^{2x}+1); monotone, |t|<1, no NaN/Inf for any finite x
    float e = __expf(2.0f * x);
    return 1.0f - 2.0f / (e + 1.0f);
}

__device__ __forceinline__ ushort f2bf(float f) {
    union { float f; unsigned u; } v; v.f = f;
    unsigned r = v.u + 0x7fffu + ((v.u >> 16) & 1u);  // RNE (prepack only)
    return (ushort)(r >> 16);
}

__device__ __forceinline__ float bf2f(ushort h) {
    union { unsigned u; float f; } v; v.u = ((unsigned)h) << 16;
    return v.f;
}

// lgkm-only barrier (CK idiom): LDS handoff without draining vmcnt —
// in-flight global prefetches (weights, next-phase act) survive the barrier.
__device__ __forceinline__ void block_sync_lds() {
    asm volatile("s_waitcnt lgkmcnt(0)" ::: "memory");
    __builtin_amdgcn_s_barrier();
    asm volatile("" ::: "memory");
}

// T0..T7 of tanh(hv), packed to 8 bf16 in an int4: round-half-up + v_perm pack
__device__ __forceinline__ int4v cheb_pack(float hv) {
    float t = fast_tanh(hv);
    float t2 = t + t;
    unsigned u[8];
    union { float f; unsigned q; } c;
    u[0] = 0x3f800000u;              // T0 = 1.0
    c.f = t; u[1] = c.q;             // T1 = t
    float Tm = 1.0f, Tc = t;
#pragma unroll
    for (int d = 2; d < 8; ++d) {
        float Tn = fmaf(t2, Tc, -Tm);   // T_d = 2t*T_{d-1} - T_{d-2}
        c.f = Tn; u[d] = c.q;
        Tm = Tc; Tc = Tn;
    }
#pragma unroll
    for (int i = 0; i < 8; ++i) u[i] += 0x8000u;   // round-half-up to bf16
    int4v p;
    p.x = (int)__builtin_amdgcn_perm(u[1], u[0], 0x07060302);
    p.y = (int)__builtin_amdgcn_perm(u[3], u[2], 0x07060302);
    p.z = (int)__builtin_amdgcn_perm(u[5], u[4], 0x07060302);
    p.w = (int)__builtin_amdgcn_perm(u[7], u[6], 0x07060302);
    return p;
}

// ---------------------------------------------------------------- RFF embed (transposed out)
__global__ __launch_bounds__(256) void kan_rff(
    const float* __restrict__ x, const float* __restrict__ B, float* __restrict__ hT)
{
    int b = blockIdx.x * 256 + threadIdx.x;
    int j = blockIdx.y;   // 0..127
    float x0 = x[b * 3 + 0], x1 = x[b * 3 + 1], x2 = x[b * 3 + 2];
    float z = x0 * B[j] + x1 * B[128 + j] + x2 * B[256 + j];
    float sn, cs;
    __sincosf(z, &sn, &cs);
    hT[(size_t)j * BATCH + b] = cs;
    hT[(size_t)(j + 128) * BATCH + b] = sn;
}

// ------------------------------------------------- weight prepack to bf16 A-frag order
// pw[((kc*16 + nt)*64 + lane)*8 + j] = bf16( W[nt*16 + (lane&15)][kc*32 + (lane>>4)*8 + j] )
__global__ __launch_bounds__(256) void kan_prepack(
    const float* __restrict__ CU, const float* __restrict__ CV,
    const float* __restrict__ Cin, const float* __restrict__ Cout,
    ushort* __restrict__ pw)
{
    int mat = blockIdx.y;   // 0=CU 1=CV 2..5=Cin[i] 6..9=Cout[i]
    const float* src;
    if (mat == 0) src = CU;
    else if (mat == 1) src = CV;
    else if (mat < 6) src = Cin + (size_t)(mat - 2) * MAT_ELEMS;
    else src = Cout + (size_t)(mat - 6) * MAT_ELEMS;
    ushort* dst = pw + (size_t)mat * MAT_ELEMS;

    int p8 = blockIdx.x * 256 + threadIdx.x;   // 0..65535 (16B groups)
    int l  = p8 & 63;
    int nt = (p8 >> 6) & 15;
    int kc = p8 >> 10;
    int o = nt * 16 + (l & 15);
    int k = kc * 32 + ((l >> 4) << 3);
    const float* s = src + (size_t)o * KTOT + k;
    short8 v;
#pragma unroll
    for (int j = 0; j < 8; ++j) v[j] = (short)f2bf(s[j]);
    *(short8*)(dst + (size_t)p8 * 8) = v;
}

// ---------------------------------------------------------------- fused KAN GEMM
// Block = 64-batch x 128-out tile (out-split via blockIdx.y -> grid 1024,
// 4 blocks/CU for mode-1: co-resident blocks fill barrier/latency stalls).
// Basis shared block-wide (2x cheb redundancy device-wide). K phased in 8ths:
// 32 feats x 64 batch basis in 32KB LDS, then barrier-free 8-chunk MFMA run.
// Weights stream global->VGPR with PREFETCH DISTANCE 3 (4 rotating bufs,
// static indices). lgkm-only barriers keep vm prefetches in flight.
// NT=512 (uv): waves 0-3 -> U, 4-7 -> V, shared basis; bf16 outputs.
// NT=256 (res): MODE=1 epilogue out = s*(v+g*(u-v)) + (1-s)*idb (u,v bf16).
template<int NT, int MODE>
__global__ __launch_bounds__(NT, 4) void kan_gemm(
    const float* __restrict__ actT,
    const ushort* __restrict__ pw0,
    const ushort* __restrict__ pw1,
    void* out0v, void* out1v,
    const ushort* __restrict__ uT, const ushort* __restrict__ vT,
    const float* idbT, const float* __restrict__ scal)
{
    constexpr int ROWS = FPP * 64 / NT;   // feat rows per thread per phase: 8 or 4
    __shared__ __attribute__((aligned(16))) ushort bas[FPP * 64 * 8]; // 32KB

    const int tid = threadIdx.x;
    const int wv = tid >> 6, lane = tid & 63;
    const int wg = (NT == 512) ? (wv & 3) : wv;   // out-group 0..3 (32 outs each)
    const int sel = (NT == 512) ? (wv >> 2) : 0;
    const int b0 = blockIdx.x * 64;
    const int oy = blockIdx.y;                    // out half: outs oy*128 ..

    const ushort* pw = sel ? pw1 : pw0;

    f32x4 acc[2][4];   // [mf][nf] : 32 outs x 64 batch per wave
#pragma unroll
    for (int i = 0; i < 2; ++i)
#pragma unroll
        for (int j = 0; j < 4; ++j)
            acc[i][j] = (f32x4){0.f, 0.f, 0.f, 0.f};

    // --- fill role: thread covers batch bb, feats fgrp*ROWS + q (within phase)
    const int bb = tid & 63;
    const int fgrp = tid >> 6;
    const float* actcol = actT + b0 + bb;
    ushort* bw = &bas[(size_t)(fgrp * ROWS * 64 + bb) * 8];

    // --- A (weights) per-lane stream base: nt = oy*8 + wg*2 + mf
    const ushort* pA = pw + (size_t)(((oy * 8 + wg * 2) * 64) + lane) * 8;

    float hv[ROWS], hvn[ROWS];
#pragma unroll
    for (int q = 0; q < ROWS; ++q)
        hv[q] = actcol[(size_t)(fgrp * ROWS + q) * BATCH];

    // 4 rotating weight buffers, prefetch distance 3
    short8 aw[4][2];
#pragma unroll
    for (int c = 0; c < 3; ++c)
#pragma unroll
        for (int mf = 0; mf < 2; ++mf)
            aw[c][mf] = *(const short8*)(pA + (size_t)c * CHUNK_SHORTS + mf * 512);
    const ushort* pAn = pA + 3 * (size_t)CHUNK_SHORTS;   // next chunk to prefetch (kc=3)

#pragma unroll 1
    for (int phase = 0; phase < PHASES; ++phase) {
        block_sync_lds();   // all consumers of previous phase done
#pragma unroll
        for (int q = 0; q < ROWS; ++q)
            *(int4v*)(bw + q * 512) = cheb_pack(hv[q]);
        // prefetch next phase's act values (wrap at end: harmless re-read)
        {
            const int pn = (phase + 1) & (PHASES - 1);
            const float* ac = actcol + (size_t)(pn * FPP + fgrp * ROWS) * BATCH;
#pragma unroll
            for (int q = 0; q < ROWS; ++q)
                hvn[q] = ac[(size_t)q * BATCH];
        }
        block_sync_lds();   // fill visible; weight prefetches still in flight
#pragma unroll
        for (int kcl = 0; kcl < CPP; ++kcl) {
            // prefetch chunk (phase*8 + kcl + 3); tail overruns into next
            // matrix / acts: readable, never consumed
#pragma unroll
            for (int mf = 0; mf < 2; ++mf)
                aw[(kcl + 3) & 3][mf] =
                    *(const short8*)(pAn + (size_t)kcl * CHUNK_SHORTS + mf * 512);
#pragma unroll
            for (int nf = 0; nf < 4; ++nf) {
                short8 bfr = *(const short8*)&bas[
                    ((kcl * 4 + (lane >> 4)) * 64 + nf * 16 + (lane & 15)) * 8];
                acc[0][nf] = __builtin_amdgcn_mfma_f32_16x16x32_bf16(
                    aw[kcl & 3][0], bfr, acc[0][nf], 0, 0, 0);
                acc[1][nf] = __builtin_amdgcn_mfma_f32_16x16x32_bf16(
                    aw[kcl & 3][1], bfr, acc[1][nf], 0, 0, 0);
            }
        }
        pAn += CPP * (size_t)CHUNK_SHORTS;
#pragma unroll
        for (int q = 0; q < ROWS; ++q) hv[q] = hvn[q];
    }

    // --- epilogue: D row (M) = out, col (N) = batch; row=(lane>>4)*4+reg
    const int col = lane & 15;
    const int rb = (lane >> 4) * 4;
    const int obase = oy * 128 + wg * 32;
    float s = 0.f;
    if (MODE == 1) s = *scal;
#pragma unroll
    for (int mf = 0; mf < 2; ++mf) {
#pragma unroll
        for (int nf = 0; nf < 4; ++nf) {
            int b = b0 + nf * 16 + col;
#pragma unroll
            for (int r = 0; r < 4; ++r) {
                int orow = obase + mf * 16 + rb + r;
                size_t idx = (size_t)orow * BATCH + b;
                float gate = acc[mf][nf][r];
                if (MODE == 0) {
                    ushort* outp = (ushort*)(sel ? out1v : out0v);
                    union { float f; unsigned u; } cv; cv.f = gate;
                    outp[idx] = (ushort)((cv.u + 0x8000u) >> 16);   // bf16 u/v
                } else {
                    float* outp = (float*)out0v;
                    // idb may alias outp: same-thread read-then-write — safe
                    float uu = bf2f(uT[idx]), vv = bf2f(vT[idx]), id = idbT[idx];
                    outp[idx] = s * (vv + gate * (uu - vv)) + (1.0f - s) * id;
                }
            }
        }
    }
}

// ---------------------------------------------------------------- final layer (N_OUT=1)
// 256 threads: batch bb = tid&63, feat quarter fq = tid>>6; LDS reduce.
__global__ __launch_bounds__(256) void kan_final(
    const float* __restrict__ hT, const float* __restrict__ Cf, float* __restrict__ out)
{
    __shared__ float cf[KTOT];        // 8KB
    __shared__ float part[4][64];
    const int tid = threadIdx.x;
    for (int i = tid; i < KTOT; i += 256) cf[i] = Cf[i];
    __syncthreads();
    const int bb = tid & 63, fq = tid >> 6;
    const int b = blockIdx.x * 64 + bb;
    float a = 0.f;
#pragma unroll 4
    for (int i = fq * 64; i < fq * 64 + 64; ++i) {
        float t = fast_tanh(hT[(size_t)i * BATCH + b]);
        const float* c = &cf[i * 8];
        float accv = fmaf(c[1], t, c[0]);
        float t2 = t + t, Tm = 1.0f, Tc = t;
#pragma unroll
        for (int d = 2; d < 8; ++d) {
            float Tn = fmaf(t2, Tc, -Tm);
            accv = fmaf(c[d], Tn, accv);
            Tm = Tc; Tc = Tn;
        }
        a += accv;
    }
    part[fq][bb] = a;
    __syncthreads();
    if (tid < 64)
        out[blockIdx.x * 64 + tid] =
            part[0][tid] + part[1][tid] + part[2][tid] + part[3][tid];
}

// ---------------------------------------------------------------- launch
extern "C" void kernel_launch(void* const* d_in, const int* in_sizes, int n_in,
                              void* d_out, int out_size, void* d_ws, size_t ws_size,
                              hipStream_t stream)
{
    const float* x      = (const float*)d_in[0];
    const float* Brff   = (const float*)d_in[1];
    const float* CU     = (const float*)d_in[2];
    const float* CV     = (const float*)d_in[3];
    const float* Cin    = (const float*)d_in[4];
    const float* Cout   = (const float*)d_in[5];
    const float* alphas = (const float*)d_in[6];
    const float* betas  = (const float*)d_in[7];
    const float* Cf     = (const float*)d_in[8];
    float* out = (float*)d_out;

    char* ws = (char*)d_ws;
    const size_t PW_BYTES  = (size_t)10 * MAT_ELEMS * sizeof(ushort);   // 10.5 MB
    const size_t ACT_BYTES = (size_t)BATCH * NHID * sizeof(float);      // 33.5 MB
    const size_t BF_BYTES  = (size_t)BATCH * NHID * sizeof(ushort);     // 16.75 MB
    ushort* pw = (ushort*)ws;   // pw FIRST: prefetch tail overrun lands in acts
    float*  P  = (float*)(ws + PW_BYTES);                       // h ping (fp32)
    float*  Q  = (float*)(ws + PW_BYTES + ACT_BYTES);           // h pong / t1 (fp32)
    ushort* u16 = (ushort*)(ws + PW_BYTES + 2 * ACT_BYTES);     // u (bf16)
    ushort* v16 = (ushort*)(ws + PW_BYTES + 2 * ACT_BYTES + BF_BYTES); // v (bf16)

    kan_rff<<<dim3(BATCH / 256, 128), 256, 0, stream>>>(x, Brff, P);
    kan_prepack<<<dim3(256, 10), 256, 0, stream>>>(CU, CV, Cin, Cout, pw);

    // u and v in ONE dispatch: 8-wave blocks share the basis across U and V
    kan_gemm<512, 0><<<dim3(BATCH / 64, 2), 512, 0, stream>>>(
        P, pw, pw + MAT_ELEMS, u16, v16, nullptr, nullptr, nullptr, nullptr);

    for (int i = 0; i < 4; ++i) {
        const ushort* pwIn  = pw + (size_t)(2 + i) * MAT_ELEMS;
        const ushort* pwOut = pw + (size_t)(6 + i) * MAT_ELEMS;
        // t1 = beta*(v + g(h)*(u-v)) + (1-beta)*h        : act=P, out=Q
        kan_gemm<256, 1><<<dim3(BATCH / 64, 2), 256, 0, stream>>>(
            P, pwIn, nullptr, Q, nullptr, u16, v16, P, betas + i);
        // h' = alpha*(v + g(t1)*(u-v)) + (1-alpha)*h     : act=Q, idb=P, out=P
        kan_gemm<256, 1><<<dim3(BATCH / 64, 2), 256, 0, stream>>>(
            Q, pwOut, nullptr, P, nullptr, u16, v16, P, alphas + i);
    }

    kan_final<<<BATCH / 64, 256, 0, stream>>>(P, Cf, out);
}